// Round 16
// baseline (2261.713 us; speedup 1.0000x reference)
//
#include <hip/hip_runtime.h>
#include <stdint.h>

#define TOKENS 16384
#define D_IN   4096
#define D_OUT  4096
#define NKT    32   // K-tiles of 128 fp4 (2 MFMA-K-steps of 64)

typedef int   v4i  __attribute__((ext_vector_type(4)));
typedef int   v8i  __attribute__((ext_vector_type(8)));
typedef float v16f __attribute__((ext_vector_type(16)));

__device__ __forceinline__ void gl_lds16(const void* g, void* l) {
    __builtin_amdgcn_global_load_lds(
        (const __attribute__((address_space(1))) void*)g,
        (__attribute__((address_space(3))) void*)l, 16, 0, 0);
}

#define BARRIER() __builtin_amdgcn_s_barrier()

// fp4 e2m1 (OCP MXFP4): +1.0 = 0x2, -1.0 = 0xA, 0 = 0x0  [verified R13]
__device__ __forceinline__ unsigned fp4c(float f) {
    return (f > 0.f) ? 0x2u : ((f < 0.f) ? 0xAu : 0u);
}

// ---------------------------------------------------------------------------
// FP4 packed image (R13-verified, absmax=0):
// A unit (mb,KT) = 128 rows x 128 k (8 KB), B unit (nb,KT) = 256 rows x 128 k
// (16 KB): [u][ks(2)][lane(64)][16B]; lane l -> row u*32 + (l&31);
// k = KT*128 + ks*64 + (l>>5)*32 + nibble. All GEMM accesses lane-linear
// (gl_lds + ds_read_b128, 0 bank conflicts).
// ---------------------------------------------------------------------------

__global__ __launch_bounds__(256) void pack_x_abssum(
        const float* __restrict__ x, unsigned char* __restrict__ xp,
        float* __restrict__ partials) {
    __shared__ unsigned short tile16[128 * 33];
    __shared__ float wsum[4];
    const int b  = blockIdx.x;           // 4096 = 128 mb x 32 KT
    const int mb = b >> 5;
    const int KT = b & 31;
    const int t  = threadIdx.x;
    const float* src = x + (size_t)mb * 128 * D_IN + KT * 128;
    float accum = 0.f;
#pragma unroll
    for (int p = 0; p < 16; ++p) {
        const int idx = p * 256 + t;     // 128 rows x 32 float4
        const int r   = idx >> 5;
        const int c4  = idx & 31;
        float4 v = *(const float4*)(src + (size_t)r * D_IN + c4 * 4);
        tile16[r * 33 + c4] = (unsigned short)(fp4c(v.x) | (fp4c(v.y) << 4)
                             | (fp4c(v.z) << 8) | (fp4c(v.w) << 12));
        accum += fabsf(v.x) + fabsf(v.y) + fabsf(v.z) + fabsf(v.w);
    }
    __syncthreads();
    unsigned* dst = (unsigned*)(xp + ((size_t)mb * 32 + KT) * 8192);
#pragma unroll
    for (int w = 0; w < 8; ++w) {
        const int i    = w * 256 + t;    // u32 index 0..2047 (coalesced store)
        const int c    = i >> 2;         // 16-B chunk
        const int j2   = (i & 3) * 4;    // byte offset within chunk
        const int uks  = c >> 6;
        const int lane = c & 63;
        const int row  = (uks >> 1) * 32 + (lane & 31);
        const int c4a  = (uks & 1) * 16 + (lane >> 5) * 8 + (j2 >> 1);
        dst[i] = (unsigned)tile16[row * 33 + c4a]
               | ((unsigned)tile16[row * 33 + c4a + 1] << 16);
    }
#pragma unroll
    for (int o = 32; o > 0; o >>= 1) accum += __shfl_down(accum, o);
    if ((t & 63) == 0) wsum[t >> 6] = accum;
    __syncthreads();
    if (t == 0) partials[b] = wsum[0] + wsum[1] + wsum[2] + wsum[3];
}

// pack_w + (block 0 only) the partials reduction — saves a dispatch.
__global__ __launch_bounds__(256) void pack_w_kernel(
        const float* __restrict__ wsrc, unsigned char* __restrict__ wp,
        const float* __restrict__ partials, float* __restrict__ sum_ptr) {
    __shared__ unsigned short tile16[256 * 33];
    const int b  = blockIdx.x;           // 512 = 16 nb x 32 KT
    const int nb = b >> 5;
    const int KT = b & 31;
    const int t  = threadIdx.x;

    if (b == 0) {                        // reduce 4096 partials (pack_x done)
        __shared__ float ws[4];
        float a = 0.f;
        for (int i = t; i < 4096; i += 256) a += partials[i];
#pragma unroll
        for (int o = 32; o > 0; o >>= 1) a += __shfl_down(a, o);
        if ((t & 63) == 0) ws[t >> 6] = a;
        __syncthreads();
        if (t == 0) sum_ptr[0] = ws[0] + ws[1] + ws[2] + ws[3];
        __syncthreads();
    }

    const float* src = wsrc + (size_t)nb * 256 * D_IN + KT * 128;
#pragma unroll
    for (int p = 0; p < 32; ++p) {
        const int idx = p * 256 + t;     // 256 rows x 32 float4
        const int r   = idx >> 5;
        const int c4  = idx & 31;
        float4 v = *(const float4*)(src + (size_t)r * D_IN + c4 * 4);
        tile16[r * 33 + c4] = (unsigned short)(fp4c(v.x) | (fp4c(v.y) << 4)
                             | (fp4c(v.z) << 8) | (fp4c(v.w) << 12));
    }
    __syncthreads();
    unsigned* dst = (unsigned*)(wp + ((size_t)nb * 32 + KT) * 16384);
#pragma unroll
    for (int w = 0; w < 16; ++w) {
        const int i    = w * 256 + t;    // u32 index 0..4095
        const int c    = i >> 2;
        const int j2   = (i & 3) * 4;
        const int uks  = c >> 6;         // 0..15
        const int lane = c & 63;
        const int row  = (uks >> 1) * 32 + (lane & 31);
        const int c4a  = (uks & 1) * 16 + (lane >> 5) * 8 + (j2 >> 1);
        dst[i] = (unsigned)tile16[row * 33 + c4a]
               | ((unsigned)tile16[row * 33 + c4a + 1] << 16);
    }
}

// ---------------------------------------------------------------------------
// 128x256 tile, BK=128 fp4, 4 waves (2Mx2N), wave-tile 64x128,
// mfma_scale_f32_32x32x64_f8f6f4 (fmt 4/4, scales E8M0 1.0), triple-buffered
// LDS 3x24KB, 2 blocks/CU.
// R16 probe: PINNED v8i OPERAND MATERIALIZATION. The fp4 slot wall (2812cy)
// exceeds the instruction-identical i8 wall (2390cy) by ~420cy; prime
// suspect is per-MFMA re-materialization of the dup8 shufflevector (4 movs
// x 2 operands x 16 MFMA if not CSE'd). Each half-tile now builds its 6
// v8i fragments ONCE and pins them via an empty asm "+v" constraint —
// the compiler must consume the pinned registers, not re-derive.
// Rotation reverted to same-tile reads (R8 vs R6 proved rotation null) to
// keep peak live regs ~200 (acc 128 + 48 pinned + addr) — no spill risk.
// Sync: 1 barrier/tile, counted vmcnt(6) (stage(t+2) in flight), no
// explicit lgkmcnt (consumption-drained; R15-verified).
// ---------------------------------------------------------------------------

#define STAGE(d, kt) do {                                               \
    signed char* L_ = (signed char*)&ldsA[d][0];                        \
    const signed char* ga_ = aG + (size_t)(kt) * 8192;                  \
    const signed char* gb_ = bG + (size_t)(kt) * 16384;                 \
    gl_lds16(ga_ + t16,         L_ + t16);                              \
    gl_lds16(ga_ + 4096 + t16,  L_ + 4096 + t16);                      \
    gl_lds16(gb_ + t16,         L_ + 8192 + t16);                      \
    gl_lds16(gb_ + 4096 + t16,  L_ + 12288 + t16);                     \
    gl_lds16(gb_ + 8192 + t16,  L_ + 16384 + t16);                     \
    gl_lds16(gb_ + 12288 + t16, L_ + 20480 + t16);                     \
} while (0)

__device__ __forceinline__ v8i dup8(v4i v) {
    return __builtin_shufflevector(v, v, 0, 1, 2, 3, 0, 1, 2, 3);
}

#define MFMA4(d, a, b) __builtin_amdgcn_mfma_scale_f32_32x32x64_f8f6f4( \
    (a), (b), (d), 4, 4, 0, 0x7F7F7F7F, 0, 0x7F7F7F7F)

// One K=64 half-tile: read 6 frags, build+PIN 6 v8i once, 8 MFMAs.
// (ks selects the K-half; STG expands a prefetch in the ks0 instance only.)
#define TILE_HALF(L, ks, STG) do {                                      \
    v4i a0_ = L[auo + (ks) * 64 + lane];                                \
    v4i a1_ = L[auo + 128 + (ks) * 64 + lane];                          \
    v4i b0_ = L[buo + (ks) * 64 + lane];                                \
    v4i b1_ = L[buo + 128 + (ks) * 64 + lane];                          \
    v4i b2_ = L[buo + 256 + (ks) * 64 + lane];                          \
    v4i b3_ = L[buo + 384 + (ks) * 64 + lane];                          \
    STG;                                                                \
    v8i A0_ = dup8(a0_), A1_ = dup8(a1_);                               \
    v8i B0_ = dup8(b0_), B1_ = dup8(b1_), B2_ = dup8(b2_), B3_ = dup8(b3_); \
    asm volatile("" : "+v"(A0_), "+v"(A1_), "+v"(B0_), "+v"(B1_),       \
                      "+v"(B2_), "+v"(B3_));                            \
    acc[0][0] = MFMA4(acc[0][0], A0_, B0_);                             \
    acc[1][0] = MFMA4(acc[1][0], A1_, B0_);                             \
    acc[0][1] = MFMA4(acc[0][1], A0_, B1_);                             \
    acc[1][1] = MFMA4(acc[1][1], A1_, B1_);                             \
    acc[0][2] = MFMA4(acc[0][2], A0_, B2_);                             \
    acc[1][2] = MFMA4(acc[1][2], A1_, B2_);                             \
    acc[0][3] = MFMA4(acc[0][3], A0_, B3_);                             \
    acc[1][3] = MFMA4(acc[1][3], A1_, B3_);                             \
} while (0)

__global__ __launch_bounds__(256, 2) void bin_gemm(
    const unsigned char* __restrict__ Ap, const unsigned char* __restrict__ Bp,
    const float* __restrict__ bias, const float* __restrict__ sum_ptr,
    float* __restrict__ out) {
    __shared__ v4i ldsA[3][1536];          // 3 x 24KB = 72KB

    const int t    = threadIdx.x;          // 0..255
    const int t16  = t * 16;
    const int lane = t & 63;
    const int wid  = t >> 6;               // 0..3
    const int wm   = wid >> 1;             // M half: rows wm*64
    const int wn   = wid & 1;              // N half: cols wn*128
    const int auo  = (wm * 2) * 128;       // A v4i base
    const int buo  = 512 + (wn * 4) * 128; // B v4i base

    // XCD slice: xcd owns nb {2x,2x+1} (packed B slice L2-resident).
    const int bid   = blockIdx.x;          // 2048 blocks
    const int xcd   = bid & 7;
    const int local = bid >> 3;            // 0..255
    const int nb    = xcd * 2 + (local & 1);
    const int mb    = local >> 1;          // 0..127

    const signed char* aG = (const signed char*)Ap + (size_t)mb * 32 * 8192;
    const signed char* bG = (const signed char*)Bp + (size_t)nb * 32 * 16384;

    v16f acc[2][4];
#pragma unroll
    for (int i = 0; i < 2; ++i)
#pragma unroll
        for (int j = 0; j < 4; ++j) acc[i][j] = (v16f)(0.f);

    // prologue: stage kt0,kt1; wait kt0 (6 of kt1 in flight)
    STAGE(0, 0);
    STAGE(1, 1);
    asm volatile("s_waitcnt vmcnt(6)" ::: "memory");
    BARRIER();

    int cur = 0, sb = 2;
    for (int kt = 0; kt < NKT; ++kt) {
        const v4i* L = &ldsA[cur][0];
        if (kt < NKT - 2) {
            TILE_HALF(L, 0, STAGE(sb, kt + 2));
        } else {
            TILE_HALF(L, 0, (void)0);
        }
        TILE_HALF(L, 1, (void)0);

        if (kt < NKT - 1) {
            if (kt == NKT - 2) { asm volatile("s_waitcnt vmcnt(0)" ::: "memory"); }
            else               { asm volatile("s_waitcnt vmcnt(6)" ::: "memory"); }
            BARRIER();
        }
        cur = (cur == 2) ? 0 : cur + 1;
        sb  = (sb == 2) ? 0 : sb + 1;
    }

    // epilogue: out = (acc + bias) * scale
    // 32x32 C/D (shape-determined): col = lane&31, row = (g&3)+8*(g>>2)+4*(lane>>5)
    const float scale = *sum_ptr * (1.0f / 67108864.0f);
    const int rbase = mb * 128 + wm * 64 + 4 * (lane >> 5);
    const int cbase = nb * 256 + wn * 128 + (lane & 31);
#pragma unroll
    for (int an = 0; an < 4; ++an) {
        const int col = cbase + an * 32;
        const float bb = bias[col];
#pragma unroll
        for (int am = 0; am < 2; ++am) {
            const int r0 = rbase + am * 32;
#pragma unroll
            for (int g = 0; g < 16; ++g) {
                const int row = r0 + (g & 3) + 8 * (g >> 2);
                out[(size_t)row * D_OUT + col] =
                    (acc[am][an][g] + bb) * scale;
            }
        }
    }
}

extern "C" void kernel_launch(void* const* d_in, const int* in_sizes, int n_in,
                              void* d_out, int out_size, void* d_ws, size_t ws_size,
                              hipStream_t stream) {
    const float* x = (const float*)d_in[0];
    const float* W = (const float*)d_in[1];
    const float* b = (const float*)d_in[2];
    float* out = (float*)d_out;

    float* sum_ptr    = (float*)d_ws;                  // [0] result
    float* partials   = (float*)d_ws + 64;             // 4096 floats
    unsigned char* xs = (unsigned char*)d_ws + 65536;  // 32 MB fp4 image
    unsigned char* wp = xs + (size_t)128 * 32 * 8192;  // + 8 MB fp4 image

    pack_x_abssum<<<128 * 32, 256, 0, stream>>>(x, xs, partials);
    pack_w_kernel<<<16 * 32, 256, 0, stream>>>(W, wp, partials, sum_ptr);
    bin_gemm<<<2048, 256, 0, stream>>>(xs, wp, b, sum_ptr, out);
}

// Round 17
// 224.372 us; speedup vs baseline: 10.0802x; 10.0802x over previous
//
#include <hip/hip_runtime.h>
#include <stdint.h>

#define TOKENS 16384
#define D_IN   4096
#define D_OUT  4096
#define NKT    32   // K-tiles of 128 fp4 (2 MFMA-K-steps of 64)

typedef int   v4i  __attribute__((ext_vector_type(4)));
typedef int   v8i  __attribute__((ext_vector_type(8)));
typedef float v16f __attribute__((ext_vector_type(16)));

__device__ __forceinline__ void gl_lds16(const void* g, void* l) {
    __builtin_amdgcn_global_load_lds(
        (const __attribute__((address_space(1))) void*)g,
        (__attribute__((address_space(3))) void*)l, 16, 0, 0);
}

#define BARRIER() __builtin_amdgcn_s_barrier()

// fp4 e2m1 (OCP MXFP4): +1.0 = 0x2, -1.0 = 0xA, 0 = 0x0  [verified R13]
__device__ __forceinline__ unsigned fp4c(float f) {
    return (f > 0.f) ? 0x2u : ((f < 0.f) ? 0xAu : 0u);
}

// ---------------------------------------------------------------------------
// FP4 packed image (R13-verified, absmax=0):
// A unit (mb,KT) = 128 rows x 128 k (8 KB), B unit (nb,KT) = 256 rows x 128 k
// (16 KB): [u][ks(2)][lane(64)][16B]; lane l -> row u*32 + (l&31);
// k = KT*128 + ks*64 + (l>>5)*32 + nibble. All GEMM accesses lane-linear
// (gl_lds + ds_read_b128, 0 bank conflicts).
// ---------------------------------------------------------------------------

__global__ __launch_bounds__(256) void pack_x_abssum(
        const float* __restrict__ x, unsigned char* __restrict__ xp,
        float* __restrict__ partials) {
    __shared__ unsigned short tile16[128 * 33];
    __shared__ float wsum[4];
    const int b  = blockIdx.x;           // 4096 = 128 mb x 32 KT
    const int mb = b >> 5;
    const int KT = b & 31;
    const int t  = threadIdx.x;
    const float* src = x + (size_t)mb * 128 * D_IN + KT * 128;
    float accum = 0.f;
#pragma unroll
    for (int p = 0; p < 16; ++p) {
        const int idx = p * 256 + t;     // 128 rows x 32 float4
        const int r   = idx >> 5;
        const int c4  = idx & 31;
        float4 v = *(const float4*)(src + (size_t)r * D_IN + c4 * 4);
        tile16[r * 33 + c4] = (unsigned short)(fp4c(v.x) | (fp4c(v.y) << 4)
                             | (fp4c(v.z) << 8) | (fp4c(v.w) << 12));
        accum += fabsf(v.x) + fabsf(v.y) + fabsf(v.z) + fabsf(v.w);
    }
    __syncthreads();
    unsigned* dst = (unsigned*)(xp + ((size_t)mb * 32 + KT) * 8192);
#pragma unroll
    for (int w = 0; w < 8; ++w) {
        const int i    = w * 256 + t;    // u32 index 0..2047 (coalesced store)
        const int c    = i >> 2;         // 16-B chunk
        const int j2   = (i & 3) * 4;    // byte offset within chunk
        const int uks  = c >> 6;
        const int lane = c & 63;
        const int row  = (uks >> 1) * 32 + (lane & 31);
        const int c4a  = (uks & 1) * 16 + (lane >> 5) * 8 + (j2 >> 1);
        dst[i] = (unsigned)tile16[row * 33 + c4a]
               | ((unsigned)tile16[row * 33 + c4a + 1] << 16);
    }
#pragma unroll
    for (int o = 32; o > 0; o >>= 1) accum += __shfl_down(accum, o);
    if ((t & 63) == 0) wsum[t >> 6] = accum;
    __syncthreads();
    if (t == 0) partials[b] = wsum[0] + wsum[1] + wsum[2] + wsum[3];
}

// pack_w + (block 0 only) the partials reduction — saves a dispatch.
__global__ __launch_bounds__(256) void pack_w_kernel(
        const float* __restrict__ wsrc, unsigned char* __restrict__ wp,
        const float* __restrict__ partials, float* __restrict__ sum_ptr) {
    __shared__ unsigned short tile16[256 * 33];
    const int b  = blockIdx.x;           // 512 = 16 nb x 32 KT
    const int nb = b >> 5;
    const int KT = b & 31;
    const int t  = threadIdx.x;

    if (b == 0) {                        // reduce 4096 partials (pack_x done)
        __shared__ float ws[4];
        float a = 0.f;
        for (int i = t; i < 4096; i += 256) a += partials[i];
#pragma unroll
        for (int o = 32; o > 0; o >>= 1) a += __shfl_down(a, o);
        if ((t & 63) == 0) ws[t >> 6] = a;
        __syncthreads();
        if (t == 0) sum_ptr[0] = ws[0] + ws[1] + ws[2] + ws[3];
        __syncthreads();
    }

    const float* src = wsrc + (size_t)nb * 256 * D_IN + KT * 128;
#pragma unroll
    for (int p = 0; p < 32; ++p) {
        const int idx = p * 256 + t;     // 256 rows x 32 float4
        const int r   = idx >> 5;
        const int c4  = idx & 31;
        float4 v = *(const float4*)(src + (size_t)r * D_IN + c4 * 4);
        tile16[r * 33 + c4] = (unsigned short)(fp4c(v.x) | (fp4c(v.y) << 4)
                             | (fp4c(v.z) << 8) | (fp4c(v.w) << 12));
    }
    __syncthreads();
    unsigned* dst = (unsigned*)(wp + ((size_t)nb * 32 + KT) * 16384);
#pragma unroll
    for (int w = 0; w < 16; ++w) {
        const int i    = w * 256 + t;    // u32 index 0..4095
        const int c    = i >> 2;
        const int j2   = (i & 3) * 4;
        const int uks  = c >> 6;         // 0..15
        const int lane = c & 63;
        const int row  = (uks >> 1) * 32 + (lane & 31);
        const int c4a  = (uks & 1) * 16 + (lane >> 5) * 8 + (j2 >> 1);
        dst[i] = (unsigned)tile16[row * 33 + c4a]
               | ((unsigned)tile16[row * 33 + c4a + 1] << 16);
    }
}

// ---------------------------------------------------------------------------
// R15 (verified best: 225.3us total, absmax 0.0): 128x256 tile, BK=128 fp4,
// 4 waves (2Mx2N), wave-tile 64x128, mfma_scale_f32_32x32x64_f8f6f4
// (fmt 4/4, scales E8M0 1.0), triple-buffered LDS 3x24KB, 2 blocks/CU,
// cross-barrier rotation, 1 barrier/tile, counted vmcnt(6), no explicit
// pre-barrier lgkmcnt (consumption-drained — R15-verified).
// R16's asm-"+v" operand pinning REVERTED: it over-constrained the
// allocator and spilled the 128-reg accumulator to scratch (7.8 GB of
// scratch writes, 9x regression). dup8-per-use is the stable form.
// ---------------------------------------------------------------------------

#define STAGE(d, kt) do {                                               \
    signed char* L_ = (signed char*)&ldsA[d][0];                        \
    const signed char* ga_ = aG + (size_t)(kt) * 8192;                  \
    const signed char* gb_ = bG + (size_t)(kt) * 16384;                 \
    gl_lds16(ga_ + t16,         L_ + t16);                              \
    gl_lds16(ga_ + 4096 + t16,  L_ + 4096 + t16);                      \
    gl_lds16(gb_ + t16,         L_ + 8192 + t16);                      \
    gl_lds16(gb_ + 4096 + t16,  L_ + 12288 + t16);                     \
    gl_lds16(gb_ + 8192 + t16,  L_ + 16384 + t16);                     \
    gl_lds16(gb_ + 12288 + t16, L_ + 20480 + t16);                     \
} while (0)

#define READ_KS0(dst, bufv) do {                                        \
    const v4i* L_ = &ldsA[bufv][0];                                     \
    dst[0] = L_[auo + lane];            dst[1] = L_[auo + 128 + lane];  \
    dst[2] = L_[buo + lane];            dst[3] = L_[buo + 128 + lane];  \
    dst[4] = L_[buo + 256 + lane];      dst[5] = L_[buo + 384 + lane];  \
} while (0)

#define READ_KS1(dst, bufv) do {                                        \
    const v4i* L_ = &ldsA[bufv][0];                                     \
    dst[0] = L_[auo + 64 + lane];       dst[1] = L_[auo + 192 + lane];  \
    dst[2] = L_[buo + 64 + lane];       dst[3] = L_[buo + 192 + lane];  \
    dst[4] = L_[buo + 320 + lane];      dst[5] = L_[buo + 448 + lane];  \
} while (0)

__device__ __forceinline__ v8i dup8(v4i v) {
    return __builtin_shufflevector(v, v, 0, 1, 2, 3, 0, 1, 2, 3);
}

#define MFMA4(d, a, b) __builtin_amdgcn_mfma_scale_f32_32x32x64_f8f6f4( \
    (a), (b), (d), 4, 4, 0, 0x7F7F7F7F, 0, 0x7F7F7F7F)

#define CLUSTER(F) do {                                                 \
    _Pragma("unroll")                                                   \
    for (int an = 0; an < 4; ++an) {                                    \
        acc[0][an] = MFMA4(acc[0][an], dup8(F[0]), dup8(F[2 + an]));    \
        acc[1][an] = MFMA4(acc[1][an], dup8(F[1]), dup8(F[2 + an]));    \
    }                                                                   \
} while (0)

__global__ __launch_bounds__(256, 2) void bin_gemm(
    const unsigned char* __restrict__ Ap, const unsigned char* __restrict__ Bp,
    const float* __restrict__ bias, const float* __restrict__ sum_ptr,
    float* __restrict__ out) {
    __shared__ v4i ldsA[3][1536];          // 3 x 24KB = 72KB

    const int t    = threadIdx.x;          // 0..255
    const int t16  = t * 16;
    const int lane = t & 63;
    const int wid  = t >> 6;               // 0..3
    const int wm   = wid >> 1;             // M half: rows wm*64
    const int wn   = wid & 1;              // N half: cols wn*128
    const int auo  = (wm * 2) * 128;       // A v4i base
    const int buo  = 512 + (wn * 4) * 128; // B v4i base

    // XCD slice: xcd owns nb {2x,2x+1} (packed B slice L2-resident).
    const int bid   = blockIdx.x;          // 2048 blocks
    const int xcd   = bid & 7;
    const int local = bid >> 3;            // 0..255
    const int nb    = xcd * 2 + (local & 1);
    const int mb    = local >> 1;          // 0..127

    const signed char* aG = (const signed char*)Ap + (size_t)mb * 32 * 8192;
    const signed char* bG = (const signed char*)Bp + (size_t)nb * 32 * 16384;

    v16f acc[2][4];
#pragma unroll
    for (int i = 0; i < 2; ++i)
#pragma unroll
        for (int j = 0; j < 4; ++j) acc[i][j] = (v16f)(0.f);

    v4i P[6], Q[6];                        // ks0 / ks1 fragment banks

    // prologue: stage kt0,kt1; wait kt0 (6 of kt1 in flight); read tile-0 frags
    STAGE(0, 0);
    STAGE(1, 1);
    asm volatile("s_waitcnt vmcnt(6)" ::: "memory");
    BARRIER();
    READ_KS0(P, 0);
    READ_KS1(Q, 0);

    int cb = 0, rb = 1, sb = 2;
    for (int kt = 0; kt < NKT - 1; ++kt) {
        CLUSTER(P);                        // ks0(kt), inputs >=1 cluster old
        if (kt < NKT - 2) STAGE(sb, kt + 2);
        if (kt == NKT - 2) { asm volatile("s_waitcnt vmcnt(0)" ::: "memory"); }
        else               { asm volatile("s_waitcnt vmcnt(6)" ::: "memory"); }
        BARRIER();
        READ_KS0(P, rb);                   // tile kt+1 frags, consumed next iter
        CLUSTER(Q);                        // ks1(kt), inputs a full tile old
        READ_KS1(Q, rb);
        const int n0 = rb, n1 = sb, n2 = cb;
        cb = n0; rb = n1; sb = n2;
    }
    CLUSTER(P);                            // final tile
    CLUSTER(Q);

    // epilogue: out = (acc + bias) * scale
    // 32x32 C/D (shape-determined): col = lane&31, row = (g&3)+8*(g>>2)+4*(lane>>5)
    const float scale = *sum_ptr * (1.0f / 67108864.0f);
    const int rbase = mb * 128 + wm * 64 + 4 * (lane >> 5);
    const int cbase = nb * 256 + wn * 128 + (lane & 31);
#pragma unroll
    for (int an = 0; an < 4; ++an) {
        const int col = cbase + an * 32;
        const float bb = bias[col];
#pragma unroll
        for (int am = 0; am < 2; ++am) {
            const int r0 = rbase + am * 32;
#pragma unroll
            for (int g = 0; g < 16; ++g) {
                const int row = r0 + (g & 3) + 8 * (g >> 2);
                out[(size_t)row * D_OUT + col] =
                    (acc[am][an][g] + bb) * scale;
            }
        }
    }
}

extern "C" void kernel_launch(void* const* d_in, const int* in_sizes, int n_in,
                              void* d_out, int out_size, void* d_ws, size_t ws_size,
                              hipStream_t stream) {
    const float* x = (const float*)d_in[0];
    const float* W = (const float*)d_in[1];
    const float* b = (const float*)d_in[2];
    float* out = (float*)d_out;

    float* sum_ptr    = (float*)d_ws;                  // [0] result
    float* partials   = (float*)d_ws + 64;             // 4096 floats
    unsigned char* xs = (unsigned char*)d_ws + 65536;  // 32 MB fp4 image
    unsigned char* wp = xs + (size_t)128 * 32 * 8192;  // + 8 MB fp4 image

    pack_x_abssum<<<128 * 32, 256, 0, stream>>>(x, xs, partials);
    pack_w_kernel<<<16 * 32, 256, 0, stream>>>(W, wp, partials, sum_ptr);
    bin_gemm<<<2048, 256, 0, stream>>>(xs, wp, b, sum_ptr, out);
}